// Round 3
// baseline (173.295 us; speedup 1.0000x reference)
//
#include <hip/hip_runtime.h>

// One row per 32-lane half-wave; lane k owns columns [4k,4k+4) as a 16B vector.
// R3 = R2 with clang ext_vector_type instead of HIP float4 (nontemporal builtin
// requires a true vector type). Branchless-ish select with unconditional
// c0/c1/flag loads (independent -> one memory-wait per row), two rows
// interleaved per iteration for MLP, nontemporal output stores.

typedef float f32x4 __attribute__((ext_vector_type(4)));

__device__ __forceinline__ f32x4 select_row(float a, float b, float c, int ar,
                                            f32x4 x, f32x4 y,
                                            const float* __restrict__ tail) {
    f32x4 r;
    if (a > 0.0f) {
        r = x + y;
    } else if (b > 0.0f) {
        r = x * y;
    } else if (c > 0.0f) {
        if (ar == 1) r = -x;
        else         r = x - y;
    } else {
        // passthrough, ~12.5%; tail not 16B-aligned -> scalar loads
        r.x = tail[0]; r.y = tail[1]; r.z = tail[2]; r.w = tail[3];
    }
    return r;
}

__global__ __launch_bounds__(256) void interp_kernel(
    const int* __restrict__ arities,
    const float* __restrict__ inputs,     // [n, 131]
    const float* __restrict__ children,   // [2, n, 128]
    float* __restrict__ out,              // [n, 128]
    int n)
{
    const int lane = threadIdx.x & 31;
    const int wid  = threadIdx.x >> 5;
    const int rowsPerBlock = blockDim.x >> 5;   // 8
    const int stride = gridDim.x * rowsPerBlock;

    const f32x4* c0base = (const f32x4*)children;
    const f32x4* c1base = (const f32x4*)children + (size_t)n * 32;
    f32x4* outv = (f32x4*)out;

    int row = blockIdx.x * rowsPerBlock + wid;

    // main loop: two rows in flight per iteration
    for (; row + stride < n; row += 2 * stride) {
        const int rowB = row + stride;

        // --- issue ALL loads for both rows (independent) ---
        const float* inA = inputs + (size_t)row  * 131;
        const float* inB = inputs + (size_t)rowB * 131;
        float aA = inA[0], bA = inA[1], cA = inA[2];
        float aB = inB[0], bB = inB[1], cB = inB[2];
        int arA = arities[row], arB = arities[rowB];
        f32x4 xA = c0base[(size_t)row  * 32 + lane];
        f32x4 yA = c1base[(size_t)row  * 32 + lane];
        f32x4 xB = c0base[(size_t)rowB * 32 + lane];
        f32x4 yB = c1base[(size_t)rowB * 32 + lane];

        // --- compute + store ---
        f32x4 rA = select_row(aA, bA, cA, arA, xA, yA, inA + 3 + lane * 4);
        __builtin_nontemporal_store(rA, outv + (size_t)row * 32 + lane);
        f32x4 rB = select_row(aB, bB, cB, arB, xB, yB, inB + 3 + lane * 4);
        __builtin_nontemporal_store(rB, outv + (size_t)rowB * 32 + lane);
    }

    // tail: single row
    if (row < n) {
        const float* inA = inputs + (size_t)row * 131;
        float aA = inA[0], bA = inA[1], cA = inA[2];
        int arA = arities[row];
        f32x4 xA = c0base[(size_t)row * 32 + lane];
        f32x4 yA = c1base[(size_t)row * 32 + lane];
        f32x4 rA = select_row(aA, bA, cA, arA, xA, yA, inA + 3 + lane * 4);
        __builtin_nontemporal_store(rA, outv + (size_t)row * 32 + lane);
    }
}

extern "C" void kernel_launch(void* const* d_in, const int* in_sizes, int n_in,
                              void* d_out, int out_size, void* d_ws, size_t ws_size,
                              hipStream_t stream) {
    const int*   arities  = (const int*)d_in[0];
    const float* inputs   = (const float*)d_in[1];
    const float* children = (const float*)d_in[2];
    float*       out      = (float*)d_out;

    const int n = in_sizes[0];                 // N = 500000 rows
    const int block = 256;
    const int rowsPerBlock = block / 32;       // 8
    int blocksNeeded = (n + rowsPerBlock - 1) / rowsPerBlock;
    int grid = blocksNeeded < 2048 ? blocksNeeded : 2048;  // full CU wave capacity

    interp_kernel<<<grid, block, 0, stream>>>(arities, inputs, children, out, n);
}

// Round 4
// 119.921 us; speedup vs baseline: 1.4451x; 1.4451x over previous
//
#include <hip/hip_runtime.h>

// R4: one row per full 64-lane wave, lane k owns columns [2k,2k+2) as float2.
//  - Branches are wave-uniform (row is readfirstlane'd to an SGPR) -> no
//    divergence, flags/arity go through the scalar cache.
//  - Flags for row t+1 are prefetched before processing row t, so the wave
//    always has data loads in flight (breaks the flag->data serial chain).
//  - Conditional data loads keep traffic at the ~790 MB minimum.
//  - NT loads/stores for the pure streaming operands (children, out).

typedef float f32x2 __attribute__((ext_vector_type(2)));

__global__ __launch_bounds__(256) void interp_kernel(
    const int* __restrict__ arities,
    const float* __restrict__ inputs,     // [n, 131]
    const float* __restrict__ children,   // [2, n, 128]
    float* __restrict__ out,              // [n, 128]
    int n)
{
    const int lane = threadIdx.x & 63;
    const int wid  = threadIdx.x >> 6;          // wave id in block, 0..3
    const int rowsPerBlock = blockDim.x >> 6;   // 4
    const int stride = gridDim.x * rowsPerBlock;

    const f32x2* c0base = (const f32x2*)children;                     // [n][64]
    const f32x2* c1base = (const f32x2*)children + (size_t)n * 64;
    f32x2* outv = (f32x2*)out;

    int row = __builtin_amdgcn_readfirstlane(blockIdx.x * rowsPerBlock + wid);
    if (row >= n) return;

    // preload flags for the first row (uniform -> scalar loads)
    const float* inrow = inputs + (size_t)row * 131;
    float a = inrow[0], b = inrow[1], c = inrow[2];
    int ar = arities[row];

    while (true) {
        const int next = row + stride;

        // issue next row's flag loads early; they resolve during this row's data phase
        float na = 0.f, nb = 0.f, nc = 0.f;
        int nar = 0;
        if (next < n) {
            const float* nin = inputs + (size_t)next * 131;
            na = nin[0]; nb = nin[1]; nc = nin[2];
            nar = arities[next];
        }

        // process current row (wave-uniform branch -> single path, masked nothing)
        f32x2 r;
        if (a > 0.0f) {
            f32x2 x = __builtin_nontemporal_load(c0base + (size_t)row * 64 + lane);
            f32x2 y = __builtin_nontemporal_load(c1base + (size_t)row * 64 + lane);
            r = x + y;
        } else if (b > 0.0f) {
            f32x2 x = __builtin_nontemporal_load(c0base + (size_t)row * 64 + lane);
            f32x2 y = __builtin_nontemporal_load(c1base + (size_t)row * 64 + lane);
            r = x * y;
        } else if (c > 0.0f) {
            if (ar == 1) {
                f32x2 x = __builtin_nontemporal_load(c0base + (size_t)row * 64 + lane);
                r = -x;
            } else {
                f32x2 x = __builtin_nontemporal_load(c0base + (size_t)row * 64 + lane);
                f32x2 y = __builtin_nontemporal_load(c1base + (size_t)row * 64 + lane);
                r = x - y;
            }
        } else {
            // passthrough (~12.5%); shares cache lines with the flag reads
            const float* t = inputs + (size_t)row * 131 + 3 + lane * 2;
            r.x = t[0]; r.y = t[1];
        }
        __builtin_nontemporal_store(r, outv + (size_t)row * 64 + lane);

        if (next >= n) break;
        row = __builtin_amdgcn_readfirstlane(next);
        a = na; b = nb; c = nc; ar = nar;
    }
}

extern "C" void kernel_launch(void* const* d_in, const int* in_sizes, int n_in,
                              void* d_out, int out_size, void* d_ws, size_t ws_size,
                              hipStream_t stream) {
    const int*   arities  = (const int*)d_in[0];
    const float* inputs   = (const float*)d_in[1];
    const float* children = (const float*)d_in[2];
    float*       out      = (float*)d_out;

    const int n = in_sizes[0];                 // N = 500000 rows
    const int block = 256;
    const int rowsPerBlock = block / 64;       // 4 waves/block, 1 row per wave
    int blocksNeeded = (n + rowsPerBlock - 1) / rowsPerBlock;
    int grid = blocksNeeded < 2048 ? blocksNeeded : 2048;  // 8192 waves = full capacity

    interp_kernel<<<grid, block, 0, stream>>>(arities, inputs, children, out, n);
}